// Round 5
// baseline (391.395 us; speedup 1.0000x reference)
//
#include <hip/hip_runtime.h>
#include <hip/hip_bf16.h>
#include <cstdint>

#define DIM 768
#define HEADS 12
#define DH 64
#define MLP_DIM 3072
#define ROWS 8192   // 8*1024
#define SEQ 1024
#define PPAD 72     // attn P scratch row stride (elements)
#define ISTR 136    // bf16 epilogue image row stride (shorts), 272B, 16B-mult
#define FSTR 132    // fp32 epilogue image row stride (floats), 528B, 16B-mult

typedef __attribute__((ext_vector_type(8))) short bf16x8;
typedef __attribute__((ext_vector_type(4))) float f32x4;

typedef __attribute__((address_space(1))) void GV;
typedef __attribute__((address_space(3))) void SV;

__device__ inline void async16(const void* g, void* l) {
  __builtin_amdgcn_global_load_lds((GV*)(void*)g, (SV*)l, 16, 0, 0);
}

__device__ inline unsigned short f2b(float f) {
  union { float f; uint32_t u; } v; v.f = f;
  uint32_t u = v.u;
  return (unsigned short)((u + 0x7fffu + ((u >> 16) & 1u)) >> 16);
}

// fast GELU (erf via Abramowitz-Stegun 7.1.25, |eps|<=2.5e-5)
__device__ inline float gelu_f(float v) {
  float x = v * 0.70710678118654752f;
  float ax = fabsf(x);
  float t = 1.f / (1.f + 0.47047f * ax);
  float poly = t * (0.3480242f + t * (-0.0958798f + t * 0.7478556f));
  float erfv = 1.f - poly * __expf(-ax * ax);
  erfv = copysignf(erfv, x);
  return 0.5f * v * (1.f + erfv);
}

// ---------------- transpose fp32 [K][N] -> bf16 [N][K] ----------------
__global__ __launch_bounds__(256) void transpose_k(const float* __restrict__ in,
                                                   unsigned short* __restrict__ out,
                                                   int K, int N) {
  __shared__ float t[32][33];
  int tx = threadIdx.x & 31, ty = threadIdx.x >> 5;
  int bn = blockIdx.x * 32, bk = blockIdx.y * 32;
#pragma unroll
  for (int i = ty; i < 32; i += 8) t[i][tx] = in[(size_t)(bk + i) * N + bn + tx];
  __syncthreads();
#pragma unroll
  for (int i = ty; i < 32; i += 8) out[(size_t)(bn + i) * K + bk + tx] = f2b(t[tx][i]);
}

// ---------------- layernorm fp32 -> bf16, one wave per row ----------------
__global__ __launch_bounds__(256) void ln_k(const float* __restrict__ x,
                                            const float* __restrict__ g,
                                            const float* __restrict__ b,
                                            unsigned short* __restrict__ h) {
  int wave = threadIdx.x >> 6, lane = threadIdx.x & 63;
  int row = blockIdx.x * 4 + wave;
  const float* xr = x + (size_t)row * DIM;
  float v[12];
  float s = 0.f;
#pragma unroll
  for (int j = 0; j < 12; ++j) { v[j] = xr[lane + j * 64]; s += v[j]; }
#pragma unroll
  for (int m = 1; m < 64; m <<= 1) s += __shfl_xor(s, m);
  float mu = s * (1.f / DIM);
  float vs = 0.f;
#pragma unroll
  for (int j = 0; j < 12; ++j) { float d = v[j] - mu; vs += d * d; }
#pragma unroll
  for (int m = 1; m < 64; m <<= 1) vs += __shfl_xor(vs, m);
  float rstd = rsqrtf(vs * (1.f / DIM) + 1e-5f);
  unsigned short* hr = h + (size_t)row * DIM;
#pragma unroll
  for (int j = 0; j < 12; ++j) {
    int i = lane + j * 64;
    hr[i] = f2b((v[j] - mu) * rstd * g[i] + b[i]);
  }
}

// ---------------- bf16 MFMA GEMM, Bt is [N][K], BK=64, XOR-swizzled LDS ----
// Double-buffered staging; vectorized epilogues via LDS image bounce.
// MODE 0: QKV scatter (N=2304), Q pre-scaled 1/8, K/V swizzled for attn
// MODE 1: out = acc + bias + resid -> fp32 outf
// MODE 2: out = gelu(acc + bias)   -> bf16 outb (row stride MLP_DIM)
template <int MODE, int TM>
__global__ __launch_bounds__(256, 2) void gemm_k(
    const unsigned short* __restrict__ A, const unsigned short* __restrict__ Bt,
    int M, int N, int K,
    const float* __restrict__ bias, const float* __restrict__ resid,
    float* __restrict__ outf, unsigned short* __restrict__ outb,
    unsigned short* __restrict__ Qb, unsigned short* __restrict__ Kb,
    unsigned short* __restrict__ Vt) {
  constexpr int MI = (TM == 128) ? 4 : 2;
  constexpr int ASZ = TM * 64, BSZ = 128 * 64;   // shorts
  __shared__ __align__(16) unsigned short smem[2 * (ASZ + BSZ)];
  int tid = threadIdx.x;
  int wave = tid >> 6, lane = tid & 63, lrow = lane & 15, qd = lane >> 4;
  int ntn = N >> 7;
  int bm = (blockIdx.x / ntn) * TM;
  int bn = (blockIdx.x % ntn) << 7;
  int wm = (TM == 128) ? (wave >> 1) * 64 : (wave & 1) * 32;
  int wn = (TM == 128) ? (wave & 1) * 64 : (wave >> 1) * 64;

  f32x4 acc[MI][4];
#pragma unroll
  for (int i = 0; i < MI; ++i)
#pragma unroll
    for (int j = 0; j < 4; ++j) acc[i][j] = (f32x4){0.f, 0.f, 0.f, 0.f};

  int srow = tid >> 3;
  int c = (tid & 7) ^ (srow & 7);
  const char* gA = (const char*)(A + (size_t)(bm + srow) * K) + c * 16;
  const char* gB = (const char*)(Bt + (size_t)(bn + srow) * K) + c * 16;
  size_t rstep = (size_t)32 * K * 2;

  auto stage = [&](int kt, int buf) {
    size_t ko = (size_t)kt * 128;
    char* lA = (char*)(smem + (size_t)buf * (ASZ + BSZ)) + tid * 16;
    char* lB = lA + ASZ * 2;
#pragma unroll
    for (int j = 0; j < TM / 32; ++j) async16(gA + ko + j * rstep, lA + j * 4096);
#pragma unroll
    for (int j = 0; j < 4; ++j) async16(gB + ko + j * rstep, lB + j * 4096);
  };

  int nk = K >> 6;
  stage(0, 0);
  for (int kt = 0; kt < nk; ++kt) {
    asm volatile("s_waitcnt vmcnt(0)" ::: "memory");
    __syncthreads();
    if (kt + 1 < nk) stage(kt + 1, (kt + 1) & 1);
    const unsigned short* As = smem + (size_t)(kt & 1) * (ASZ + BSZ);
    const unsigned short* Bs = As + ASZ;
#pragma unroll
    for (int s = 0; s < 2; ++s) {
      int q = s * 4 + qd;
      bf16x8 af[MI], bfr[4];
#pragma unroll
      for (int i = 0; i < MI; ++i) {
        int r = wm + i * 16 + lrow;
        af[i] = *(const bf16x8*)(As + r * 64 + ((q ^ (r & 7)) << 3));
      }
#pragma unroll
      for (int i = 0; i < 4; ++i) {
        int r = wn + i * 16 + lrow;
        bfr[i] = *(const bf16x8*)(Bs + r * 64 + ((q ^ (r & 7)) << 3));
      }
#pragma unroll
      for (int mi = 0; mi < MI; ++mi)
#pragma unroll
        for (int ni = 0; ni < 4; ++ni)
          acc[mi][ni] = __builtin_amdgcn_mfma_f32_16x16x32_bf16(af[mi], bfr[ni], acc[mi][ni], 0, 0, 0);
    }
  }
  __syncthreads();   // all compute done before LDS overlay

  if (MODE == 1) {
    // fp32 image (TM=64 x 128), raw acc; bias+resid added vectorized at read-back
    float* img = (float*)smem;
#pragma unroll
    for (int mi = 0; mi < MI; ++mi)
#pragma unroll
      for (int ni = 0; ni < 4; ++ni)
#pragma unroll
        for (int r = 0; r < 4; ++r)
          img[(wm + mi * 16 + qd * 4 + r) * FSTR + wn + ni * 16 + lrow] = acc[mi][ni][r];
    __syncthreads();
    int lr = tid >> 2, cs = (tid & 3) * 32;
    const float* src = img + lr * FSTR + cs;
    float* dst = outf + (size_t)(bm + lr) * 768 + bn + cs;
    const float* bp = bias + bn + cs;
    const float* rp = resid + (size_t)(bm + lr) * 768 + bn + cs;
#pragma unroll
    for (int k = 0; k < 8; ++k) {
      f32x4 v = *(const f32x4*)(src + k * 4);
      f32x4 bb = *(const f32x4*)(bp + k * 4);
      f32x4 rr = *(const f32x4*)(rp + k * 4);
      *(f32x4*)(dst + k * 4) = v + bb + rr;
    }
  } else if (MODE == 2) {
    // bf16 image 128x128, gelu(acc+bias) at write
    unsigned short* img = smem;
#pragma unroll
    for (int mi = 0; mi < MI; ++mi)
#pragma unroll
      for (int ni = 0; ni < 4; ++ni)
#pragma unroll
        for (int r = 0; r < 4; ++r) {
          int lc = wn + ni * 16 + lrow;
          float v = acc[mi][ni][r] + bias[bn + lc];
          img[(wm + mi * 16 + qd * 4 + r) * ISTR + lc] = f2b(gelu_f(v));
        }
    __syncthreads();
#pragma unroll
    for (int p = 0; p < 2; ++p) {
      int lr = p * 64 + (tid >> 2);
      int cs = (tid & 3) * 32;
      const unsigned short* src = img + lr * ISTR + cs;
      unsigned short* dst = outb + (size_t)(bm + lr) * MLP_DIM + bn + cs;
#pragma unroll
      for (int k = 0; k < 4; ++k) *(uint4*)(dst + k * 8) = *(const uint4*)(src + k * 8);
    }
  } else {
    // MODE 0: QKV scatter. Tile lies entirely in Q, K, or V (128 | 768).
    int which = bn / 768;
    int rem_base = bn - which * 768;
    unsigned short* img = smem;
    if (which < 2) {
      // normal orientation; Q pre-scaled
#pragma unroll
      for (int mi = 0; mi < MI; ++mi)
#pragma unroll
        for (int ni = 0; ni < 4; ++ni)
#pragma unroll
          for (int r = 0; r < 4; ++r) {
            float v = acc[mi][ni][r];
            if (which == 0) v *= 0.125f;
            img[(wm + mi * 16 + qd * 4 + r) * ISTR + wn + ni * 16 + lrow] = f2b(v);
          }
      __syncthreads();
      int lr = tid >> 1, hseg = tid & 1;
      int hh = rem_base / 64 + hseg;
      int b = (bm + lr) >> 10, n = (bm + lr) & 1023;
      size_t bh = (size_t)(b * HEADS + hh);
      const unsigned short* src = img + lr * ISTR + hseg * 64;
      unsigned short* dst = (which == 0 ? Qb : Kb) + (bh * SEQ + n) * DH;
      if (which == 0) {
#pragma unroll
        for (int j = 0; j < 8; ++j) *(uint4*)(dst + j * 8) = *(const uint4*)(src + j * 8);
      } else {
        int nx = n & 7;
#pragma unroll
        for (int j = 0; j < 8; ++j) *(uint4*)(dst + ((j ^ nx) * 8)) = *(const uint4*)(src + j * 8);
      }
    } else {
      // V: write image transposed (lane's 4 r-values -> one b64), rows become dh
#pragma unroll
      for (int mi = 0; mi < MI; ++mi)
#pragma unroll
        for (int ni = 0; ni < 4; ++ni) {
          int lc = wn + ni * 16 + lrow;
          int rbase = wm + mi * 16 + qd * 4;
          uint2 pk;
          pk.x = (uint32_t)f2b(acc[mi][ni][0]) | ((uint32_t)f2b(acc[mi][ni][1]) << 16);
          pk.y = (uint32_t)f2b(acc[mi][ni][2]) | ((uint32_t)f2b(acc[mi][ni][3]) << 16);
          *(uint2*)(img + lc * ISTR + rbase) = pk;
        }
      __syncthreads();
      int d = tid >> 1, nh = tid & 1;          // d: 0..127 (2 heads x 64 dh)
      int hh = rem_base / 64 + (d >> 6);
      int dhl = d & 63;
      int b = bm >> 10;
      size_t bh = (size_t)(b * HEADS + hh);
      const unsigned short* src = img + d * ISTR + nh * 64;
      unsigned short* dst = Vt + (bh * DH + dhl) * SEQ + (bm & 1023) + nh * 64;
      int dx = dhl & 7;
#pragma unroll
      for (int j = 0; j < 8; ++j) *(uint4*)(dst + ((j ^ dx) * 8)) = *(const uint4*)(src + j * 8);
    }
  }
}

// ---------------- flash attention v2 (unchanged) ----------------
__global__ __launch_bounds__(256, 3) void attn_k(const unsigned short* __restrict__ Qb,
                                                 const unsigned short* __restrict__ Kb,
                                                 const unsigned short* __restrict__ Vt,
                                                 unsigned short* __restrict__ o) {
  __shared__ __align__(16) unsigned short Ks[2][64 * 64];
  __shared__ __align__(16) unsigned short Vs[2][64 * 64];
  __shared__ __align__(16) unsigned short Pa[4][32 * PPAD];
  int tid = threadIdx.x;
  int wave = tid >> 6, lane = tid & 63;
  int lrow = lane & 15, qd = lane >> 4;
  int bh = blockIdx.x % 96;
  int qt = blockIdx.x / 96;
  int b = bh / HEADS, hh = bh % HEADS;
  const unsigned short* Qh = Qb + (size_t)bh * SEQ * DH;
  const char* Kh = (const char*)(Kb + (size_t)bh * SEQ * DH);
  const char* Vh = (const char*)(Vt + (size_t)bh * DH * SEQ);
  int qw = qt * 128 + wave * 32;

  bf16x8 qf[2][2];
#pragma unroll
  for (int qs = 0; qs < 2; ++qs)
#pragma unroll
    for (int hf = 0; hf < 2; ++hf)
      qf[qs][hf] = *(const bf16x8*)(Qh + (qw + qs * 16 + lrow) * DH + hf * 32 + qd * 8);

  f32x4 oacc[2][4];
#pragma unroll
  for (int qs = 0; qs < 2; ++qs)
#pragma unroll
    for (int d = 0; d < 4; ++d) oacc[qs][d] = (f32x4){0.f, 0.f, 0.f, 0.f};
  float li[2] = {0.f, 0.f};
  unsigned short* Pw = Pa[wave];

  auto stage = [&](int t, int buf) {
    const char* kbase = Kh + (size_t)t * 8192;
    char* kd = (char*)Ks[buf];
    async16(kbase + tid * 16, kd + tid * 16);
    async16(kbase + 4096 + tid * 16, kd + 4096 + tid * 16);
    const char* vbase = Vh + (size_t)t * 128;
    char* vd = (char*)Vs[buf];
    async16(vbase + (size_t)(tid >> 3) * 2048 + (tid & 7) * 16, vd + tid * 16);
    async16(vbase + (size_t)((tid >> 3) + 32) * 2048 + (tid & 7) * 16, vd + 4096 + tid * 16);
  };

  stage(0, 0);
  for (int t = 0; t < 16; ++t) {
    asm volatile("s_waitcnt vmcnt(0)" ::: "memory");
    __syncthreads();
    if (t < 15) stage(t + 1, (t + 1) & 1);
    const unsigned short* Kst = Ks[t & 1];
    const unsigned short* Vst = Vs[t & 1];

    f32x4 st[4][2];
#pragma unroll
    for (int kt = 0; kt < 4; ++kt) {
      int krow = kt * 16 + lrow;
      int ksw = krow & 7;
      const unsigned short* Kr = Kst + krow * 64;
      bf16x8 k0 = *(const bf16x8*)(Kr + ((qd ^ ksw) << 3));
      bf16x8 k1 = *(const bf16x8*)(Kr + (((qd + 4) ^ ksw) << 3));
#pragma unroll
      for (int qs = 0; qs < 2; ++qs) {
        f32x4 z = (f32x4){0.f, 0.f, 0.f, 0.f};
        z = __builtin_amdgcn_mfma_f32_16x16x32_bf16(k0, qf[qs][0], z, 0, 0, 0);
        z = __builtin_amdgcn_mfma_f32_16x16x32_bf16(k1, qf[qs][1], z, 0, 0, 0);
        st[kt][qs] = z;
      }
    }

#pragma unroll
    for (int kt = 0; kt < 4; ++kt)
#pragma unroll
      for (int qs = 0; qs < 2; ++qs) {
        float p0 = __expf(st[kt][qs][0]);
        float p1 = __expf(st[kt][qs][1]);
        float p2 = __expf(st[kt][qs][2]);
        float p3 = __expf(st[kt][qs][3]);
        li[qs] += (p0 + p1) + (p2 + p3);
        uint2 pk;
        pk.x = (uint32_t)f2b(p0) | ((uint32_t)f2b(p1) << 16);
        pk.y = (uint32_t)f2b(p2) | ((uint32_t)f2b(p3) << 16);
        *(uint2*)(Pw + (qs * 16 + lrow) * PPAD + kt * 16 + qd * 4) = pk;
      }
    asm volatile("s_waitcnt lgkmcnt(0)" ::: "memory");

    bf16x8 ap[2][2];
#pragma unroll
    for (int qs = 0; qs < 2; ++qs)
#pragma unroll
      for (int kh = 0; kh < 2; ++kh)
        ap[qs][kh] = *(const bf16x8*)(Pw + (qs * 16 + lrow) * PPAD + kh * 32 + qd * 8);

#pragma unroll
    for (int ds = 0; ds < 4; ++ds) {
      int vrow = ds * 16 + lrow;
      int vsw = vrow & 7;
      const unsigned short* Vr = Vst + vrow * 64;
      bf16x8 v0 = *(const bf16x8*)(Vr + ((qd ^ vsw) << 3));
      bf16x8 v1 = *(const bf16x8*)(Vr + (((4 + qd) ^ vsw) << 3));
#pragma unroll
      for (int qs = 0; qs < 2; ++qs) {
        oacc[qs][ds] = __builtin_amdgcn_mfma_f32_16x16x32_bf16(ap[qs][0], v0, oacc[qs][ds], 0, 0, 0);
        oacc[qs][ds] = __builtin_amdgcn_mfma_f32_16x16x32_bf16(ap[qs][1], v1, oacc[qs][ds], 0, 0, 0);
      }
    }
  }

#pragma unroll
  for (int qs = 0; qs < 2; ++qs) {
    li[qs] += __shfl_xor(li[qs], 16);
    li[qs] += __shfl_xor(li[qs], 32);
  }

#pragma unroll
  for (int qs = 0; qs < 2; ++qs)
#pragma unroll
    for (int r = 0; r < 4; ++r) {
      float inv = 1.f / __shfl(li[qs], qd * 4 + r);
      int n = qw + qs * 16 + qd * 4 + r;
#pragma unroll
      for (int ds = 0; ds < 4; ++ds) {
        int dh = ds * 16 + lrow;
        o[((size_t)(b * SEQ + n)) * DIM + hh * DH + dh] = f2b(oacc[qs][ds][r] * inv);
      }
    }
}

extern "C" void kernel_launch(void* const* d_in, const int* in_sizes, int n_in,
                              void* d_out, int out_size, void* d_ws, size_t ws_size,
                              hipStream_t stream) {
  const float* x     = (const float*)d_in[0];
  const float* ln1_g = (const float*)d_in[1];
  const float* ln1_b = (const float*)d_in[2];
  const float* w_qkv = (const float*)d_in[3];
  const float* w_out = (const float*)d_in[4];
  const float* b_out = (const float*)d_in[5];
  const float* ln2_g = (const float*)d_in[6];
  const float* ln2_b = (const float*)d_in[7];
  const float* w1    = (const float*)d_in[8];
  const float* b1    = (const float*)d_in[9];
  const float* w2    = (const float*)d_in[10];
  const float* b2    = (const float*)d_in[11];

  char* ws = (char*)d_ws;
  unsigned short* wqkvT = (unsigned short*)(ws + 0);
  unsigned short* woutT = (unsigned short*)(ws + 3538944);
  unsigned short* w1T   = (unsigned short*)(ws + 4718592);
  unsigned short* w2T   = (unsigned short*)(ws + 9437184);
  float*          x2    = (float*)(ws + 14155776);
  unsigned short* h     = (unsigned short*)(ws + 39321600);
  char* big = ws + 51904512;
  unsigned short* Qb = (unsigned short*)(big);
  unsigned short* Kb = (unsigned short*)(big + 12582912);
  unsigned short* Vt = (unsigned short*)(big + 25165824);
  unsigned short* ob = (unsigned short*)(big + 37748736);
  unsigned short* am = (unsigned short*)(big);

  transpose_k<<<dim3(72, 24), 256, 0, stream>>>(w_qkv, wqkvT, 768, 2304);
  transpose_k<<<dim3(24, 24), 256, 0, stream>>>(w_out, woutT, 768, 768);
  transpose_k<<<dim3(96, 24), 256, 0, stream>>>(w1, w1T, 768, 3072);
  transpose_k<<<dim3(24, 96), 256, 0, stream>>>(w2, w2T, 3072, 768);

  ln_k<<<2048, 256, 0, stream>>>(x, ln1_g, ln1_b, h);
  gemm_k<0, 128><<<64 * 18, 256, 0, stream>>>(h, wqkvT, ROWS, 2304, 768,
                                              nullptr, nullptr, nullptr, nullptr, Qb, Kb, Vt);
  attn_k<<<768, 256, 0, stream>>>(Qb, Kb, Vt, ob);
  gemm_k<1, 64><<<128 * 6, 256, 0, stream>>>(ob, woutT, ROWS, 768, 768,
                                             b_out, x, x2, nullptr, nullptr, nullptr, nullptr);
  ln_k<<<2048, 256, 0, stream>>>(x2, ln2_g, ln2_b, h);
  gemm_k<2, 128><<<64 * 24, 256, 0, stream>>>(h, w1T, ROWS, 3072, 768,
                                              b1, nullptr, nullptr, am, nullptr, nullptr, nullptr);
  gemm_k<1, 64><<<128 * 6, 256, 0, stream>>>(am, w2T, ROWS, 768, 3072,
                                             b2, x2, (float*)d_out, nullptr, nullptr, nullptr, nullptr);
}

// Round 6
// 374.020 us; speedup vs baseline: 1.0465x; 1.0465x over previous
//
#include <hip/hip_runtime.h>
#include <hip/hip_bf16.h>
#include <cstdint>

#define DIM 768
#define HEADS 12
#define DH 64
#define MLP_DIM 3072
#define ROWS 8192   // 8*1024
#define SEQ 1024
#define PPAD 72     // attn P scratch row stride (elements)
#define ISTR 136    // bf16 epilogue image row stride (shorts)

typedef __attribute__((ext_vector_type(8))) short bf16x8;
typedef __attribute__((ext_vector_type(4))) float f32x4;

typedef __attribute__((address_space(1))) void GV;
typedef __attribute__((address_space(3))) void SV;

__device__ inline void async16(const void* g, void* l) {
  __builtin_amdgcn_global_load_lds((GV*)(void*)g, (SV*)l, 16, 0, 0);
}

__device__ inline unsigned short f2b(float f) {
  union { float f; uint32_t u; } v; v.f = f;
  uint32_t u = v.u;
  return (unsigned short)((u + 0x7fffu + ((u >> 16) & 1u)) >> 16);
}

// fast GELU (erf via Abramowitz-Stegun 7.1.25, |eps|<=2.5e-5)
__device__ inline float gelu_f(float v) {
  float x = v * 0.70710678118654752f;
  float ax = fabsf(x);
  float t = 1.f / (1.f + 0.47047f * ax);
  float poly = t * (0.3480242f + t * (-0.0958798f + t * 0.7478556f));
  float erfv = 1.f - poly * __expf(-ax * ax);
  erfv = copysignf(erfv, x);
  return 0.5f * v * (1.f + erfv);
}

// ---------------- transpose fp32 [K][N] -> bf16 [N][K] ----------------
__global__ __launch_bounds__(256) void transpose_k(const float* __restrict__ in,
                                                   unsigned short* __restrict__ out,
                                                   int K, int N) {
  __shared__ float t[32][33];
  int tx = threadIdx.x & 31, ty = threadIdx.x >> 5;
  int bn = blockIdx.x * 32, bk = blockIdx.y * 32;
#pragma unroll
  for (int i = ty; i < 32; i += 8) t[i][tx] = in[(size_t)(bk + i) * N + bn + tx];
  __syncthreads();
#pragma unroll
  for (int i = ty; i < 32; i += 8) out[(size_t)(bn + i) * K + bk + tx] = f2b(t[tx][i]);
}

// ---------------- layernorm fp32 -> bf16, one wave per row ----------------
__global__ __launch_bounds__(256) void ln_k(const float* __restrict__ x,
                                            const float* __restrict__ g,
                                            const float* __restrict__ b,
                                            unsigned short* __restrict__ h) {
  int wave = threadIdx.x >> 6, lane = threadIdx.x & 63;
  int row = blockIdx.x * 4 + wave;
  const float* xr = x + (size_t)row * DIM;
  float v[12];
  float s = 0.f;
#pragma unroll
  for (int j = 0; j < 12; ++j) { v[j] = xr[lane + j * 64]; s += v[j]; }
#pragma unroll
  for (int m = 1; m < 64; m <<= 1) s += __shfl_xor(s, m);
  float mu = s * (1.f / DIM);
  float vs = 0.f;
#pragma unroll
  for (int j = 0; j < 12; ++j) { float d = v[j] - mu; vs += d * d; }
#pragma unroll
  for (int m = 1; m < 64; m <<= 1) vs += __shfl_xor(vs, m);
  float rstd = rsqrtf(vs * (1.f / DIM) + 1e-5f);
  unsigned short* hr = h + (size_t)row * DIM;
#pragma unroll
  for (int j = 0; j < 12; ++j) {
    int i = lane + j * 64;
    hr[i] = f2b((v[j] - mu) * rstd * g[i] + b[i]);
  }
}

// ---------------- gemm1: 64x128 block, 256 thr, single-buffer (round-4) ----
// out = acc + bias + resid -> fp32 outf   (proj, MLP2)
__global__ __launch_bounds__(256, 2) void gemm1_k(
    const unsigned short* __restrict__ A, const unsigned short* __restrict__ Bt,
    int N, int K,
    const float* __restrict__ bias, const float* __restrict__ resid,
    float* __restrict__ outf) {
  __shared__ __align__(16) unsigned short As[64 * 64];
  __shared__ __align__(16) unsigned short Bs[128 * 64];
  int tid = threadIdx.x;
  int wave = tid >> 6, lane = tid & 63, lrow = lane & 15, qd = lane >> 4;
  int ntn = N >> 7;
  int bm = (blockIdx.x / ntn) * 64;
  int bn = (blockIdx.x % ntn) << 7;
  int wm = (wave & 1) * 32;
  int wn = (wave >> 1) * 64;

  f32x4 acc[2][4];
#pragma unroll
  for (int i = 0; i < 2; ++i)
#pragma unroll
    for (int j = 0; j < 4; ++j) acc[i][j] = (f32x4){0.f, 0.f, 0.f, 0.f};

  int srow = tid >> 3;
  int c = (tid & 7) ^ (srow & 7);
  const char* gA = (const char*)(A + (size_t)(bm + srow) * K) + c * 16;
  const char* gB = (const char*)(Bt + (size_t)(bn + srow) * K) + c * 16;
  char* lA = (char*)As + tid * 16;
  char* lB = (char*)Bs + tid * 16;
  size_t rstep = (size_t)32 * K * 2;

  int nk = K >> 6;
  for (int kt = 0; kt < nk; ++kt) {
    size_t ko = (size_t)kt * 128;
#pragma unroll
    for (int j = 0; j < 2; ++j) async16(gA + ko + j * rstep, lA + j * 4096);
#pragma unroll
    for (int j = 0; j < 4; ++j) async16(gB + ko + j * rstep, lB + j * 4096);
    asm volatile("s_waitcnt vmcnt(0)" ::: "memory");
    __syncthreads();
#pragma unroll
    for (int s = 0; s < 2; ++s) {
      int q = s * 4 + qd;
      bf16x8 af[2], bfr[4];
#pragma unroll
      for (int i = 0; i < 2; ++i) {
        int r = wm + i * 16 + lrow;
        af[i] = *(const bf16x8*)(As + r * 64 + ((q ^ (r & 7)) << 3));
      }
#pragma unroll
      for (int i = 0; i < 4; ++i) {
        int r = wn + i * 16 + lrow;
        bfr[i] = *(const bf16x8*)(Bs + r * 64 + ((q ^ (r & 7)) << 3));
      }
#pragma unroll
      for (int mi = 0; mi < 2; ++mi)
#pragma unroll
        for (int ni = 0; ni < 4; ++ni)
          acc[mi][ni] = __builtin_amdgcn_mfma_f32_16x16x32_bf16(af[mi], bfr[ni], acc[mi][ni], 0, 0, 0);
    }
    __syncthreads();
  }

#pragma unroll
  for (int mi = 0; mi < 2; ++mi)
#pragma unroll
    for (int ni = 0; ni < 4; ++ni)
#pragma unroll
      for (int r = 0; r < 4; ++r) {
        int row = bm + wm + mi * 16 + qd * 4 + r;
        int col = bn + wn + ni * 16 + lrow;
        float v = acc[mi][ni][r] + bias[col] + resid[(size_t)row * 768 + col];
        outf[(size_t)row * 768 + col] = v;
      }
}

// ---------------- gemm2: 128x128 block, 128 thr / 2 waves, wave 64x128 -----
// Single-buffered; 12 LDS frags per 32 MFMA (0.375 reads/MFMA).
// MODE 0: QKV scatter (N=2304), Q pre-scaled 1/8, K/V swizzled for attn
// MODE 2: out = gelu(acc + bias) -> bf16 outb (row stride MLP_DIM)
template <int MODE>
__global__ __launch_bounds__(128, 2) void gemm2_k(
    const unsigned short* __restrict__ A, const unsigned short* __restrict__ Bt,
    int N, int K,
    const float* __restrict__ bias, unsigned short* __restrict__ outb,
    unsigned short* __restrict__ Qb, unsigned short* __restrict__ Kb,
    unsigned short* __restrict__ Vt) {
  __shared__ __align__(16) unsigned short smem[128 * ISTR];  // >= 16384 stage shorts
  int tid = threadIdx.x;
  int wave = tid >> 6, lane = tid & 63, lrow = lane & 15, qd = lane >> 4;
  int ntn = N >> 7;
  int bm = (blockIdx.x / ntn) << 7;
  int bn = (blockIdx.x % ntn) << 7;
  int wm = wave * 64;

  f32x4 acc[4][8];
#pragma unroll
  for (int i = 0; i < 4; ++i)
#pragma unroll
    for (int j = 0; j < 8; ++j) acc[i][j] = (f32x4){0.f, 0.f, 0.f, 0.f};

  // staging: 128 threads, 16 rows per issue, 8 issues each for A and B
  int srow = tid >> 3;               // 0..15
  int c = (tid & 7) ^ (srow & 7);    // XOR-swizzled source chunk
  const char* gA = (const char*)(A + (size_t)(bm + srow) * K) + c * 16;
  const char* gB = (const char*)(Bt + (size_t)(bn + srow) * K) + c * 16;
  char* lA = (char*)smem + tid * 16;
  char* lB = (char*)smem + 16384 + tid * 16;
  size_t rstep = (size_t)16 * K * 2;

  const unsigned short* As = smem;
  const unsigned short* Bs = smem + 8192;

  int nk = K >> 6;
  for (int kt = 0; kt < nk; ++kt) {
    size_t ko = (size_t)kt * 128;
#pragma unroll
    for (int j = 0; j < 8; ++j) async16(gA + ko + j * rstep, lA + j * 2048);
#pragma unroll
    for (int j = 0; j < 8; ++j) async16(gB + ko + j * rstep, lB + j * 2048);
    asm volatile("s_waitcnt vmcnt(0)" ::: "memory");
    __syncthreads();
#pragma unroll
    for (int s = 0; s < 2; ++s) {
      int q = s * 4 + qd;
      bf16x8 af[4], bfr[8];
#pragma unroll
      for (int i = 0; i < 4; ++i) {
        int r = wm + i * 16 + lrow;
        af[i] = *(const bf16x8*)(As + r * 64 + ((q ^ (r & 7)) << 3));
      }
#pragma unroll
      for (int i = 0; i < 8; ++i) {
        int r = i * 16 + lrow;
        bfr[i] = *(const bf16x8*)(Bs + r * 64 + ((q ^ (r & 7)) << 3));
      }
#pragma unroll
      for (int mi = 0; mi < 4; ++mi)
#pragma unroll
        for (int ni = 0; ni < 8; ++ni)
          acc[mi][ni] = __builtin_amdgcn_mfma_f32_16x16x32_bf16(af[mi], bfr[ni], acc[mi][ni], 0, 0, 0);
    }
    __syncthreads();
  }

  unsigned short* img = smem;
  if (MODE == 2) {
    // bf16 image 128x128 with gelu(acc+bias)
#pragma unroll
    for (int mi = 0; mi < 4; ++mi)
#pragma unroll
      for (int ni = 0; ni < 8; ++ni)
#pragma unroll
        for (int r = 0; r < 4; ++r) {
          int lc = ni * 16 + lrow;
          float v = acc[mi][ni][r] + bias[bn + lc];
          img[(wm + mi * 16 + qd * 4 + r) * ISTR + lc] = f2b(gelu_f(v));
        }
    __syncthreads();
#pragma unroll
    for (int p = 0; p < 4; ++p) {
      int lr = p * 32 + (tid >> 2);
      int cs = (tid & 3) * 32;
      const unsigned short* src = img + lr * ISTR + cs;
      unsigned short* dst = outb + (size_t)(bm + lr) * MLP_DIM + bn + cs;
#pragma unroll
      for (int k = 0; k < 4; ++k) *(uint4*)(dst + k * 8) = *(const uint4*)(src + k * 8);
    }
  } else {
    // MODE 0: QKV scatter; tile lies entirely in Q, K, or V (128 | 768)
    int which = bn / 768;
    int rem_base = bn - which * 768;
    if (which < 2) {
#pragma unroll
      for (int mi = 0; mi < 4; ++mi)
#pragma unroll
        for (int ni = 0; ni < 8; ++ni)
#pragma unroll
          for (int r = 0; r < 4; ++r) {
            float v = acc[mi][ni][r];
            if (which == 0) v *= 0.125f;
            img[(wm + mi * 16 + qd * 4 + r) * ISTR + ni * 16 + lrow] = f2b(v);
          }
      __syncthreads();
      int lr = tid;
      int b = (bm + lr) >> 10, n = (bm + lr) & 1023;
#pragma unroll
      for (int hseg = 0; hseg < 2; ++hseg) {
        int hh = rem_base / 64 + hseg;
        size_t bh = (size_t)(b * HEADS + hh);
        const unsigned short* src = img + lr * ISTR + hseg * 64;
        unsigned short* dst = (which == 0 ? Qb : Kb) + (bh * SEQ + n) * DH;
        if (which == 0) {
#pragma unroll
          for (int j = 0; j < 8; ++j) *(uint4*)(dst + j * 8) = *(const uint4*)(src + j * 8);
        } else {
          int nx = n & 7;
#pragma unroll
          for (int j = 0; j < 8; ++j) *(uint4*)(dst + ((j ^ nx) * 8)) = *(const uint4*)(src + j * 8);
        }
      }
    } else {
      // V: write image transposed (rows become dh, cols become keys)
#pragma unroll
      for (int mi = 0; mi < 4; ++mi)
#pragma unroll
        for (int ni = 0; ni < 8; ++ni) {
          int lc = ni * 16 + lrow;
          int rbase = wm + mi * 16 + qd * 4;
          uint2 pk;
          pk.x = (uint32_t)f2b(acc[mi][ni][0]) | ((uint32_t)f2b(acc[mi][ni][1]) << 16);
          pk.y = (uint32_t)f2b(acc[mi][ni][2]) | ((uint32_t)f2b(acc[mi][ni][3]) << 16);
          *(uint2*)(img + lc * ISTR + rbase) = pk;
        }
      __syncthreads();
      int d = tid;                              // 0..127: 2 heads x 64 dh
      int hh = rem_base / 64 + (d >> 6);
      int dhl = d & 63;
      int b = bm >> 10;
      size_t bh = (size_t)(b * HEADS + hh);
      const unsigned short* src = img + d * ISTR;
      int dx = dhl & 7;
#pragma unroll
      for (int nh = 0; nh < 2; ++nh) {
        unsigned short* dst = Vt + (bh * DH + dhl) * SEQ + (bm & 1023) + nh * 64;
#pragma unroll
        for (int j = 0; j < 8; ++j)
          *(uint4*)(dst + ((j ^ dx) * 8)) = *(const uint4*)(src + nh * 64 + j * 8);
      }
    }
  }
}

// ---------------- flash attention v2 (round-4, unchanged) ----------------
__global__ __launch_bounds__(256, 3) void attn_k(const unsigned short* __restrict__ Qb,
                                                 const unsigned short* __restrict__ Kb,
                                                 const unsigned short* __restrict__ Vt,
                                                 unsigned short* __restrict__ o) {
  __shared__ __align__(16) unsigned short Ks[2][64 * 64];
  __shared__ __align__(16) unsigned short Vs[2][64 * 64];
  __shared__ __align__(16) unsigned short Pa[4][32 * PPAD];
  int tid = threadIdx.x;
  int wave = tid >> 6, lane = tid & 63;
  int lrow = lane & 15, qd = lane >> 4;
  int bh = blockIdx.x % 96;
  int qt = blockIdx.x / 96;
  int b = bh / HEADS, hh = bh % HEADS;
  const unsigned short* Qh = Qb + (size_t)bh * SEQ * DH;
  const char* Kh = (const char*)(Kb + (size_t)bh * SEQ * DH);
  const char* Vh = (const char*)(Vt + (size_t)bh * DH * SEQ);
  int qw = qt * 128 + wave * 32;

  bf16x8 qf[2][2];
#pragma unroll
  for (int qs = 0; qs < 2; ++qs)
#pragma unroll
    for (int hf = 0; hf < 2; ++hf)
      qf[qs][hf] = *(const bf16x8*)(Qh + (qw + qs * 16 + lrow) * DH + hf * 32 + qd * 8);

  f32x4 oacc[2][4];
#pragma unroll
  for (int qs = 0; qs < 2; ++qs)
#pragma unroll
    for (int d = 0; d < 4; ++d) oacc[qs][d] = (f32x4){0.f, 0.f, 0.f, 0.f};
  float li[2] = {0.f, 0.f};
  unsigned short* Pw = Pa[wave];

  auto stage = [&](int t, int buf) {
    const char* kbase = Kh + (size_t)t * 8192;
    char* kd = (char*)Ks[buf];
    async16(kbase + tid * 16, kd + tid * 16);
    async16(kbase + 4096 + tid * 16, kd + 4096 + tid * 16);
    const char* vbase = Vh + (size_t)t * 128;
    char* vd = (char*)Vs[buf];
    async16(vbase + (size_t)(tid >> 3) * 2048 + (tid & 7) * 16, vd + tid * 16);
    async16(vbase + (size_t)((tid >> 3) + 32) * 2048 + (tid & 7) * 16, vd + 4096 + tid * 16);
  };

  stage(0, 0);
  for (int t = 0; t < 16; ++t) {
    asm volatile("s_waitcnt vmcnt(0)" ::: "memory");
    __syncthreads();
    if (t < 15) stage(t + 1, (t + 1) & 1);
    const unsigned short* Kst = Ks[t & 1];
    const unsigned short* Vst = Vs[t & 1];

    f32x4 st[4][2];
#pragma unroll
    for (int kt = 0; kt < 4; ++kt) {
      int krow = kt * 16 + lrow;
      int ksw = krow & 7;
      const unsigned short* Kr = Kst + krow * 64;
      bf16x8 k0 = *(const bf16x8*)(Kr + ((qd ^ ksw) << 3));
      bf16x8 k1 = *(const bf16x8*)(Kr + (((qd + 4) ^ ksw) << 3));
#pragma unroll
      for (int qs = 0; qs < 2; ++qs) {
        f32x4 z = (f32x4){0.f, 0.f, 0.f, 0.f};
        z = __builtin_amdgcn_mfma_f32_16x16x32_bf16(k0, qf[qs][0], z, 0, 0, 0);
        z = __builtin_amdgcn_mfma_f32_16x16x32_bf16(k1, qf[qs][1], z, 0, 0, 0);
        st[kt][qs] = z;
      }
    }

#pragma unroll
    for (int kt = 0; kt < 4; ++kt)
#pragma unroll
      for (int qs = 0; qs < 2; ++qs) {
        float p0 = __expf(st[kt][qs][0]);
        float p1 = __expf(st[kt][qs][1]);
        float p2 = __expf(st[kt][qs][2]);
        float p3 = __expf(st[kt][qs][3]);
        li[qs] += (p0 + p1) + (p2 + p3);
        uint2 pk;
        pk.x = (uint32_t)f2b(p0) | ((uint32_t)f2b(p1) << 16);
        pk.y = (uint32_t)f2b(p2) | ((uint32_t)f2b(p3) << 16);
        *(uint2*)(Pw + (qs * 16 + lrow) * PPAD + kt * 16 + qd * 4) = pk;
      }
    asm volatile("s_waitcnt lgkmcnt(0)" ::: "memory");

    bf16x8 ap[2][2];
#pragma unroll
    for (int qs = 0; qs < 2; ++qs)
#pragma unroll
      for (int kh = 0; kh < 2; ++kh)
        ap[qs][kh] = *(const bf16x8*)(Pw + (qs * 16 + lrow) * PPAD + kh * 32 + qd * 8);

#pragma unroll
    for (int ds = 0; ds < 4; ++ds) {
      int vrow = ds * 16 + lrow;
      int vsw = vrow & 7;
      const unsigned short* Vr = Vst + vrow * 64;
      bf16x8 v0 = *(const bf16x8*)(Vr + ((qd ^ vsw) << 3));
      bf16x8 v1 = *(const bf16x8*)(Vr + (((4 + qd) ^ vsw) << 3));
#pragma unroll
      for (int qs = 0; qs < 2; ++qs) {
        oacc[qs][ds] = __builtin_amdgcn_mfma_f32_16x16x32_bf16(ap[qs][0], v0, oacc[qs][ds], 0, 0, 0);
        oacc[qs][ds] = __builtin_amdgcn_mfma_f32_16x16x32_bf16(ap[qs][1], v1, oacc[qs][ds], 0, 0, 0);
      }
    }
  }

#pragma unroll
  for (int qs = 0; qs < 2; ++qs) {
    li[qs] += __shfl_xor(li[qs], 16);
    li[qs] += __shfl_xor(li[qs], 32);
  }

#pragma unroll
  for (int qs = 0; qs < 2; ++qs)
#pragma unroll
    for (int r = 0; r < 4; ++r) {
      float inv = 1.f / __shfl(li[qs], qd * 4 + r);
      int n = qw + qs * 16 + qd * 4 + r;
#pragma unroll
      for (int ds = 0; ds < 4; ++ds) {
        int dh = ds * 16 + lrow;
        o[((size_t)(b * SEQ + n)) * DIM + hh * DH + dh] = f2b(oacc[qs][ds][r] * inv);
      }
    }
}

extern "C" void kernel_launch(void* const* d_in, const int* in_sizes, int n_in,
                              void* d_out, int out_size, void* d_ws, size_t ws_size,
                              hipStream_t stream) {
  const float* x     = (const float*)d_in[0];
  const float* ln1_g = (const float*)d_in[1];
  const float* ln1_b = (const float*)d_in[2];
  const float* w_qkv = (const float*)d_in[3];
  const float* w_out = (const float*)d_in[4];
  const float* b_out = (const float*)d_in[5];
  const float* ln2_g = (const float*)d_in[6];
  const float* ln2_b = (const float*)d_in[7];
  const float* w1    = (const float*)d_in[8];
  const float* b1    = (const float*)d_in[9];
  const float* w2    = (const float*)d_in[10];
  const float* b2    = (const float*)d_in[11];

  char* ws = (char*)d_ws;
  unsigned short* wqkvT = (unsigned short*)(ws + 0);
  unsigned short* woutT = (unsigned short*)(ws + 3538944);
  unsigned short* w1T   = (unsigned short*)(ws + 4718592);
  unsigned short* w2T   = (unsigned short*)(ws + 9437184);
  float*          x2    = (float*)(ws + 14155776);
  unsigned short* h     = (unsigned short*)(ws + 39321600);
  char* big = ws + 51904512;
  unsigned short* Qb = (unsigned short*)(big);
  unsigned short* Kb = (unsigned short*)(big + 12582912);
  unsigned short* Vt = (unsigned short*)(big + 25165824);
  unsigned short* ob = (unsigned short*)(big + 37748736);
  unsigned short* am = (unsigned short*)(big);

  transpose_k<<<dim3(72, 24), 256, 0, stream>>>(w_qkv, wqkvT, 768, 2304);
  transpose_k<<<dim3(24, 24), 256, 0, stream>>>(w_out, woutT, 768, 768);
  transpose_k<<<dim3(96, 24), 256, 0, stream>>>(w1, w1T, 768, 3072);
  transpose_k<<<dim3(24, 96), 256, 0, stream>>>(w2, w2T, 3072, 768);

  ln_k<<<2048, 256, 0, stream>>>(x, ln1_g, ln1_b, h);
  gemm2_k<0><<<64 * 18, 128, 0, stream>>>(h, wqkvT, 2304, 768,
                                          nullptr, nullptr, Qb, Kb, Vt);
  attn_k<<<768, 256, 0, stream>>>(Qb, Kb, Vt, ob);
  gemm1_k<<<128 * 6, 256, 0, stream>>>(ob, woutT, 768, 768, b_out, x, x2);
  ln_k<<<2048, 256, 0, stream>>>(x2, ln2_g, ln2_b, h);
  gemm2_k<2><<<64 * 24, 128, 0, stream>>>(h, w1T, 3072, 768,
                                          b1, am, nullptr, nullptr, nullptr);
  gemm1_k<<<128 * 6, 256, 0, stream>>>(am, w2T, 768, 3072, b2, x2, (float*)d_out);
}